// Round 1
// baseline (302.038 us; speedup 1.0000x reference)
//
#include <hip/hip_runtime.h>
#include <math.h>

#define EMBED 256
#define HEADS 8
#define PDIM  32
#define BATCH 2
#define SEQ   1728            // 12*12*12
#define NTOK  (BATCH*SEQ)     // 3456

// ---------------------------------------------------------------------------
// Kernel 1: fused QKV projection.  C = x @ W + b, scattered to [B][H][S][P].
// grid (NTOK/64, EMBED/64, 3), block 256.  64x64 tile, 4x4 micro, BK=32.
// ---------------------------------------------------------------------------
__global__ __launch_bounds__(256) void qkv_proj_kernel(
    const float* __restrict__ x,
    const float* __restrict__ Wq, const float* __restrict__ bq,
    const float* __restrict__ Wk, const float* __restrict__ bk,
    const float* __restrict__ Wv, const float* __restrict__ bv,
    float* __restrict__ qo, float* __restrict__ ko, float* __restrict__ vo)
{
    const int z = blockIdx.z;
    const float* __restrict__ W    = (z == 0) ? Wq : (z == 1) ? Wk : Wv;
    const float* __restrict__ bias = (z == 0) ? bq : (z == 1) ? bk : bv;
    float* __restrict__ dst        = (z == 0) ? qo : (z == 1) ? ko : vo;

    const int r0 = blockIdx.x * 64;
    const int c0 = blockIdx.y * 64;
    const int t  = threadIdx.x;
    const int tx = t & 15, ty = t >> 4;

    __shared__ float AsT[32][68];   // [kk][row], stride 68: b128 reads aligned+conflict-free
    __shared__ float Bs [32][68];   // [kk][col]

    float acc[4][4] = {};

    for (int k0 = 0; k0 < EMBED; k0 += 32) {
        {   // stage A transposed: x[r0+row][k0+kk] -> AsT[kk][row]
            const int i  = t >> 3;
            const int kb = (t & 7) << 2;
            #pragma unroll
            for (int rep = 0; rep < 2; ++rep) {
                const int row = i + rep * 32;
                const float4 val = *(const float4*)&x[(size_t)(r0 + row) * EMBED + k0 + kb];
                AsT[kb + 0][row] = val.x; AsT[kb + 1][row] = val.y;
                AsT[kb + 2][row] = val.z; AsT[kb + 3][row] = val.w;
            }
            // stage B natural: W[k0+kk][c0+c] -> Bs[kk][c]
            const int kk = t >> 4;
            const int cb = (t & 15) << 2;
            #pragma unroll
            for (int rep = 0; rep < 2; ++rep) {
                const int kkk = kk + rep * 16;
                *(float4*)&Bs[kkk][cb] =
                    *(const float4*)&W[(size_t)(k0 + kkk) * EMBED + c0 + cb];
            }
        }
        __syncthreads();
        #pragma unroll
        for (int kk = 0; kk < 32; ++kk) {
            const float4 av  = *(const float4*)&AsT[kk][ty << 2];
            const float4 bv4 = *(const float4*)&Bs [kk][tx << 2];
            const float a[4] = {av.x, av.y, av.z, av.w};
            const float b[4] = {bv4.x, bv4.y, bv4.z, bv4.w};
            #pragma unroll
            for (int rr = 0; rr < 4; ++rr)
                #pragma unroll
                for (int cc = 0; cc < 4; ++cc)
                    acc[rr][cc] += a[rr] * b[cc];
        }
        __syncthreads();
    }

    // epilogue: head-split scatter [B][H][S][P]; 4-col chunk never crosses a head
    const int cbase = c0 + (tx << 2);
    const int h = cbase >> 5;
    const int p = cbase & 31;
    const float4 bb = *(const float4*)&bias[cbase];
    #pragma unroll
    for (int rr = 0; rr < 4; ++rr) {
        const int n = r0 + (ty << 2) + rr;
        const int b = n / SEQ, s = n % SEQ;
        float4 val;
        val.x = acc[rr][0] + bb.x; val.y = acc[rr][1] + bb.y;
        val.z = acc[rr][2] + bb.z; val.w = acc[rr][3] + bb.w;
        *(float4*)&dst[(((size_t)(b * HEADS + h)) * SEQ + s) * PDIM + p] = val;
    }
}

// ---------------------------------------------------------------------------
// Kernel 2: flash attention, fp32.  grid (SEQ/64, B*H), block 256.
// TQ=TK=64. Scores: 4x4 micro per thread (ty=row-group, tx=col-group).
// Online softmax entirely in registers + 16-lane butterfly shuffles.
// PV: probs round-trip through LDS; thread owns 4 rows x 2 out-dims.
// Output written as [B][S][H][P] (== [N][E]) for the final projection.
// ---------------------------------------------------------------------------
__global__ __launch_bounds__(256) void attn_kernel(
    const float* __restrict__ q, const float* __restrict__ k,
    const float* __restrict__ v, float* __restrict__ ao)
{
    const int bh = blockIdx.y;
    const int b = bh >> 3, h = bh & 7;
    const int q0 = blockIdx.x * 64;
    const int t  = threadIdx.x;
    const int tx = t & 15, ty = t >> 4;

    const float* __restrict__ qb = q + (size_t)bh * SEQ * PDIM;
    const float* __restrict__ kb = k + (size_t)bh * SEQ * PDIM;
    const float* __restrict__ vb = v + (size_t)bh * SEQ * PDIM;

    __shared__ float QsT[PDIM][68];   // [p][qrow]
    __shared__ float KsT[PDIM][68];   // [p][krow]
    __shared__ float Vs [64][PDIM];   // [krow][p]
    __shared__ float Ps [64][68];     // probs [qrow][krow]

    {   // stage Q transposed, once
        const int j  = t >> 3;
        const int pv = (t & 7) << 2;
        #pragma unroll
        for (int rep = 0; rep < 2; ++rep) {
            const int row = j + rep * 32;
            const float4 val = *(const float4*)&qb[(size_t)(q0 + row) * PDIM + pv];
            QsT[pv + 0][row] = val.x; QsT[pv + 1][row] = val.y;
            QsT[pv + 2][row] = val.z; QsT[pv + 3][row] = val.w;
        }
    }

    float m_run[4], l_run[4], acc[4][2];
    #pragma unroll
    for (int rr = 0; rr < 4; ++rr) {
        m_run[rr] = -INFINITY; l_run[rr] = 0.f;
        acc[rr][0] = 0.f; acc[rr][1] = 0.f;
    }

    for (int kt = 0; kt < SEQ / 64; ++kt) {
        const int j0 = kt * 64;
        __syncthreads();   // [A] staging vs previous iteration's reads
        {
            const int j  = t >> 3;
            const int pv = (t & 7) << 2;
            #pragma unroll
            for (int rep = 0; rep < 2; ++rep) {
                const int row = j + rep * 32;
                const float4 kv = *(const float4*)&kb[(size_t)(j0 + row) * PDIM + pv];
                KsT[pv + 0][row] = kv.x; KsT[pv + 1][row] = kv.y;
                KsT[pv + 2][row] = kv.z; KsT[pv + 3][row] = kv.w;
                *(float4*)&Vs[row][pv] = *(const float4*)&vb[(size_t)(j0 + row) * PDIM + pv];
            }
        }
        __syncthreads();   // [B]

        // ---- scores: s[4ty+rr][4tx+cc] = Q . K ----
        float sreg[4][4] = {};
        #pragma unroll
        for (int kk = 0; kk < PDIM; ++kk) {
            const float4 av  = *(const float4*)&QsT[kk][ty << 2];
            const float4 bv4 = *(const float4*)&KsT[kk][tx << 2];
            const float a[4]  = {av.x, av.y, av.z, av.w};
            const float bb2[4] = {bv4.x, bv4.y, bv4.z, bv4.w};
            #pragma unroll
            for (int rr = 0; rr < 4; ++rr)
                #pragma unroll
                for (int cc = 0; cc < 4; ++cc)
                    sreg[rr][cc] += a[rr] * bb2[cc];
        }

        // ---- online softmax, registers + butterfly over the 16 tx lanes ----
        #pragma unroll
        for (int rr = 0; rr < 4; ++rr) {
            float mt = fmaxf(fmaxf(sreg[rr][0], sreg[rr][1]),
                             fmaxf(sreg[rr][2], sreg[rr][3]));
            #pragma unroll
            for (int d = 1; d < 16; d <<= 1)
                mt = fmaxf(mt, __shfl_xor(mt, d));
            const float mnew = fmaxf(m_run[rr], mt);
            float pv4[4], ls = 0.f;
            #pragma unroll
            for (int cc = 0; cc < 4; ++cc) {
                pv4[cc] = __expf(sreg[rr][cc] - mnew);
                ls += pv4[cc];
            }
            #pragma unroll
            for (int d = 1; d < 16; d <<= 1)
                ls += __shfl_xor(ls, d);
            const float alpha = __expf(m_run[rr] - mnew);  // first tile: exp(-inf)=0
            acc[rr][0] *= alpha; acc[rr][1] *= alpha;
            l_run[rr] = l_run[rr] * alpha + ls;
            m_run[rr] = mnew;
            float4 st; st.x = pv4[0]; st.y = pv4[1]; st.z = pv4[2]; st.w = pv4[3];
            *(float4*)&Ps[(ty << 2) + rr][tx << 2] = st;
        }
        __syncthreads();   // [C] probs visible to all

        // ---- PV: acc[rr][0..1] += sum_j p[i][j] * V[j][2tx..2tx+1] ----
        #pragma unroll
        for (int jv = 0; jv < 16; ++jv) {
            float pf[4][4];
            #pragma unroll
            for (int rr = 0; rr < 4; ++rr) {
                const float4 val = *(const float4*)&Ps[(ty << 2) + rr][jv << 2];
                pf[rr][0] = val.x; pf[rr][1] = val.y;
                pf[rr][2] = val.z; pf[rr][3] = val.w;
            }
            #pragma unroll
            for (int u = 0; u < 4; ++u) {
                const float2 vv = *(const float2*)&Vs[(jv << 2) + u][tx << 1];
                #pragma unroll
                for (int rr = 0; rr < 4; ++rr) {
                    acc[rr][0] += pf[rr][u] * vv.x;
                    acc[rr][1] += pf[rr][u] * vv.y;
                }
            }
        }
    }

    #pragma unroll
    for (int rr = 0; rr < 4; ++rr) {
        const int s = q0 + (ty << 2) + rr;
        const float inv = 1.0f / l_run[rr];
        float2 o; o.x = acc[rr][0] * inv; o.y = acc[rr][1] * inv;
        *(float2*)&ao[(((size_t)b * SEQ + s) * HEADS + h) * PDIM + (tx << 1)] = o;
    }
}

// ---------------------------------------------------------------------------
// Kernel 3: output projection.  out = ao[N,E] @ Wo + bo, row-major out.
// ---------------------------------------------------------------------------
__global__ __launch_bounds__(256) void out_proj_kernel(
    const float* __restrict__ a, const float* __restrict__ Wo,
    const float* __restrict__ bo, float* __restrict__ out)
{
    const int r0 = blockIdx.x * 64;
    const int c0 = blockIdx.y * 64;
    const int t  = threadIdx.x;
    const int tx = t & 15, ty = t >> 4;

    __shared__ float AsT[32][68];
    __shared__ float Bs [32][68];

    float acc[4][4] = {};

    for (int k0 = 0; k0 < EMBED; k0 += 32) {
        {
            const int i  = t >> 3;
            const int kb = (t & 7) << 2;
            #pragma unroll
            for (int rep = 0; rep < 2; ++rep) {
                const int row = i + rep * 32;
                const float4 val = *(const float4*)&a[(size_t)(r0 + row) * EMBED + k0 + kb];
                AsT[kb + 0][row] = val.x; AsT[kb + 1][row] = val.y;
                AsT[kb + 2][row] = val.z; AsT[kb + 3][row] = val.w;
            }
            const int kk = t >> 4;
            const int cb = (t & 15) << 2;
            #pragma unroll
            for (int rep = 0; rep < 2; ++rep) {
                const int kkk = kk + rep * 16;
                *(float4*)&Bs[kkk][cb] =
                    *(const float4*)&Wo[(size_t)(k0 + kkk) * EMBED + c0 + cb];
            }
        }
        __syncthreads();
        #pragma unroll
        for (int kk = 0; kk < 32; ++kk) {
            const float4 av  = *(const float4*)&AsT[kk][ty << 2];
            const float4 bv4 = *(const float4*)&Bs [kk][tx << 2];
            const float aa[4] = {av.x, av.y, av.z, av.w};
            const float bb[4] = {bv4.x, bv4.y, bv4.z, bv4.w};
            #pragma unroll
            for (int rr = 0; rr < 4; ++rr)
                #pragma unroll
                for (int cc = 0; cc < 4; ++cc)
                    acc[rr][cc] += aa[rr] * bb[cc];
        }
        __syncthreads();
    }

    const int cbase = c0 + (tx << 2);
    const float4 bb = *(const float4*)&bo[cbase];
    #pragma unroll
    for (int rr = 0; rr < 4; ++rr) {
        const int n = r0 + (ty << 2) + rr;
        float4 val;
        val.x = acc[rr][0] + bb.x; val.y = acc[rr][1] + bb.y;
        val.z = acc[rr][2] + bb.z; val.w = acc[rr][3] + bb.w;
        *(float4*)&out[(size_t)n * EMBED + cbase] = val;
    }
}

// ---------------------------------------------------------------------------
extern "C" void kernel_launch(void* const* d_in, const int* in_sizes, int n_in,
                              void* d_out, int out_size, void* d_ws, size_t ws_size,
                              hipStream_t stream)
{
    const float* x  = (const float*)d_in[0];
    const float* Wq = (const float*)d_in[1];
    const float* bq = (const float*)d_in[2];
    const float* Wk = (const float*)d_in[3];
    const float* bk = (const float*)d_in[4];
    const float* Wv = (const float*)d_in[5];
    const float* bv = (const float*)d_in[6];
    const float* Wo = (const float*)d_in[7];
    const float* bo = (const float*)d_in[8];
    float* out = (float*)d_out;

    float* ws = (float*)d_ws;
    float* qbuf = ws;                         // [B][H][S][P]
    float* kbuf = ws + (size_t)NTOK * EMBED;  // [B][H][S][P]
    float* vbuf = ws + 2 * (size_t)NTOK * EMBED;
    float* ao   = ws + 3 * (size_t)NTOK * EMBED;  // [B][S][H][P]

    qkv_proj_kernel<<<dim3(NTOK / 64, EMBED / 64, 3), 256, 0, stream>>>(
        x, Wq, bq, Wk, bk, Wv, bv, qbuf, kbuf, vbuf);
    attn_kernel<<<dim3(SEQ / 64, BATCH * HEADS), 256, 0, stream>>>(
        qbuf, kbuf, vbuf, ao);
    out_proj_kernel<<<dim3(NTOK / 64, EMBED / 64), 256, 0, stream>>>(
        ao, Wo, bo, out);
}

// Round 2
// 148.852 us; speedup vs baseline: 2.0291x; 2.0291x over previous
//
#include <hip/hip_runtime.h>
#include <math.h>

#define EMBED 256
#define HEADS 8
#define PDIM  32
#define BATCH 2
#define SEQ   1728            // 12*12*12
#define NTOK  (BATCH*SEQ)     // 3456
#define LOG2E 1.44269504088896f

typedef __attribute__((ext_vector_type(8))) __bf16 bf16x8;
typedef __attribute__((ext_vector_type(4))) float  f32x4;
typedef unsigned short ushort_t;

static __device__ __forceinline__ unsigned short f2bf_rne(float f) {
    union { float f; unsigned u; } x; x.f = f;
    unsigned r = x.u + 0x7fffu + ((x.u >> 16) & 1u);
    return (unsigned short)(r >> 16);
}

// ---------------------------------------------------------------------------
// Kernel 1: fused QKV projection (fp32 compute).  Epilogue converts to bf16:
//   Q,K -> [b][h][s][p]   V -> transposed [b][h][p][s] (for PV B-operand reads)
// grid (NTOK/64, EMBED/64, 3), block 256.  64x64 tile, 4x4 micro, BK=32.
// ---------------------------------------------------------------------------
__global__ __launch_bounds__(256) void qkv_proj_kernel(
    const float* __restrict__ x,
    const float* __restrict__ Wq, const float* __restrict__ bq,
    const float* __restrict__ Wk, const float* __restrict__ bk,
    const float* __restrict__ Wv, const float* __restrict__ bv,
    ushort_t* __restrict__ qo, ushort_t* __restrict__ ko, ushort_t* __restrict__ vo)
{
    const int z = blockIdx.z;
    const float* __restrict__ W    = (z == 0) ? Wq : (z == 1) ? Wk : Wv;
    const float* __restrict__ bias = (z == 0) ? bq : (z == 1) ? bk : bv;

    const int r0 = blockIdx.x * 64;
    const int c0 = blockIdx.y * 64;
    const int t  = threadIdx.x;
    const int tx = t & 15, ty = t >> 4;

    __shared__ float AsT[32][68];
    __shared__ float Bs [32][68];

    float acc[4][4] = {};

    for (int k0 = 0; k0 < EMBED; k0 += 32) {
        {
            const int i  = t >> 3;
            const int kb = (t & 7) << 2;
            #pragma unroll
            for (int rep = 0; rep < 2; ++rep) {
                const int row = i + rep * 32;
                const float4 val = *(const float4*)&x[(size_t)(r0 + row) * EMBED + k0 + kb];
                AsT[kb + 0][row] = val.x; AsT[kb + 1][row] = val.y;
                AsT[kb + 2][row] = val.z; AsT[kb + 3][row] = val.w;
            }
            const int kk = t >> 4;
            const int cb = (t & 15) << 2;
            #pragma unroll
            for (int rep = 0; rep < 2; ++rep) {
                const int kkk = kk + rep * 16;
                *(float4*)&Bs[kkk][cb] =
                    *(const float4*)&W[(size_t)(k0 + kkk) * EMBED + c0 + cb];
            }
        }
        __syncthreads();
        #pragma unroll
        for (int kk = 0; kk < 32; ++kk) {
            const float4 av  = *(const float4*)&AsT[kk][ty << 2];
            const float4 bv4 = *(const float4*)&Bs [kk][tx << 2];
            const float a[4] = {av.x, av.y, av.z, av.w};
            const float b[4] = {bv4.x, bv4.y, bv4.z, bv4.w};
            #pragma unroll
            for (int rr = 0; rr < 4; ++rr)
                #pragma unroll
                for (int cc = 0; cc < 4; ++cc)
                    acc[rr][cc] += a[rr] * b[cc];
        }
        __syncthreads();
    }

    const int cbase = c0 + (tx << 2);
    const int h = cbase >> 5;
    const int p = cbase & 31;
    const float4 bb = *(const float4*)&bias[cbase];
    const int n0 = r0 + (ty << 2);
    const int b  = n0 / SEQ;
    const int s0 = n0 % SEQ;      // n0..n0+3 share b (SEQ % 4 == 0)

    if (z <= 1) {
        ushort_t* __restrict__ dst = (z == 0) ? qo : ko;
        #pragma unroll
        for (int rr = 0; rr < 4; ++rr) {
            ushort4 w;
            w.x = f2bf_rne(acc[rr][0] + bb.x);
            w.y = f2bf_rne(acc[rr][1] + bb.y);
            w.z = f2bf_rne(acc[rr][2] + bb.z);
            w.w = f2bf_rne(acc[rr][3] + bb.w);
            *(ushort4*)&dst[(((size_t)(b * HEADS + h)) * SEQ + (s0 + rr)) * PDIM + p] = w;
        }
    } else {
        const float bias4[4] = {bb.x, bb.y, bb.z, bb.w};
        #pragma unroll
        for (int cc = 0; cc < 4; ++cc) {
            ushort4 w;                         // 4 consecutive s for one p
            w.x = f2bf_rne(acc[0][cc] + bias4[cc]);
            w.y = f2bf_rne(acc[1][cc] + bias4[cc]);
            w.z = f2bf_rne(acc[2][cc] + bias4[cc]);
            w.w = f2bf_rne(acc[3][cc] + bias4[cc]);
            *(ushort4*)&vo[(((size_t)(b * HEADS + h)) * PDIM + (p + cc)) * SEQ + s0] = w;
        }
    }
}

// ---------------------------------------------------------------------------
// Kernel 2: flash attention, bf16 MFMA.  One wave (64 thr) per 16 query rows.
// grid (SEQ/16, B*H), block 64.  S^T = K*Q^T so softmax stats are per-lane
// (i = lane&15); P transposed C->A via per-wave LDS round trip; K/V fragments
// read directly from global (L2-resident), register double-buffered.
// Output ao fp32 [b][s][h][p].
// ---------------------------------------------------------------------------
__global__ __launch_bounds__(64) void attn_kernel(
    const ushort_t* __restrict__ q, const ushort_t* __restrict__ k,
    const ushort_t* __restrict__ vt, float* __restrict__ ao)
{
    const int lane = threadIdx.x;
    const int li   = lane & 15;
    const int quad = lane >> 4;
    const int bh = blockIdx.y;
    const int b  = bh >> 3, h = bh & 7;
    const int q0 = blockIdx.x * 16;

    const ushort_t* __restrict__ qb = q  + (size_t)bh * SEQ * PDIM;
    const ushort_t* __restrict__ kb = k  + (size_t)bh * SEQ * PDIM;
    const ushort_t* __restrict__ vb = vt + (size_t)bh * PDIM * SEQ;

    __shared__ ushort_t Ps[16][72];   // [i][j], pad 72 to break pow2 banks

    // Q B-frag (hoisted): B[k=quad*8+jj][n=li] = Q[q0+li][quad*8+jj]
    const bf16x8 qfrag = *(const bf16x8*)(qb + (size_t)(q0 + li) * PDIM + quad * 8);

    // per-lane fragment base pointers
    const ushort_t* kptr = kb + (size_t)li * PDIM + quad * 8;   // + (j0+16jt)*PDIM
    const ushort_t* vptr = vb + (size_t)li * SEQ + quad * 8;    // + pt*16*SEQ + j0 + 32c

    f32x4 o0 = {0.f, 0.f, 0.f, 0.f};  // p = li      (pt=0)
    f32x4 o1 = {0.f, 0.f, 0.f, 0.f};  // p = 16+li   (pt=1)
    float m_run = -__builtin_inff(), l_run = 0.f;

    bf16x8 kf0[4], vf0[4], kf1[4], vf1[4];

#define LOAD_TILE(KF, VF, J0) do {                                           \
        const ushort_t* kp = kptr + (size_t)(J0) * PDIM;                     \
        KF[0] = *(const bf16x8*)(kp);                                        \
        KF[1] = *(const bf16x8*)(kp + 16 * PDIM);                            \
        KF[2] = *(const bf16x8*)(kp + 32 * PDIM);                            \
        KF[3] = *(const bf16x8*)(kp + 48 * PDIM);                            \
        const ushort_t* vp = vptr + (J0);                                    \
        VF[0] = *(const bf16x8*)(vp);                 /* c=0, pt=0 */        \
        VF[1] = *(const bf16x8*)(vp + 16 * SEQ);      /* c=0, pt=1 */        \
        VF[2] = *(const bf16x8*)(vp + 32);            /* c=1, pt=0 */        \
        VF[3] = *(const bf16x8*)(vp + 32 + 16 * SEQ); /* c=1, pt=1 */        \
    } while (0)

    auto compute_tile = [&](const bf16x8* kf, const bf16x8* vf) {
        const f32x4 zero = {0.f, 0.f, 0.f, 0.f};
        f32x4 st[4];
        #pragma unroll
        for (int jt = 0; jt < 4; ++jt)   // S^T: A=K rows, B=Q
            st[jt] = __builtin_amdgcn_mfma_f32_16x16x32_bf16(kf[jt], qfrag, zero, 0, 0, 0);

        // row-max over j for fixed i=li: in-lane 16 vals + quad butterfly
        float tm = st[0][0];
        #pragma unroll
        for (int jt = 0; jt < 4; ++jt)
            #pragma unroll
            for (int r = 0; r < 4; ++r) tm = fmaxf(tm, st[jt][r]);
        tm = fmaxf(tm, __shfl_xor(tm, 16));
        tm = fmaxf(tm, __shfl_xor(tm, 32));
        const float mnew  = fmaxf(m_run, tm);
        const float negml = -(mnew * LOG2E);

        float ps = 0.f;
        #pragma unroll
        for (int jt = 0; jt < 4; ++jt) {
            const float p0 = __builtin_amdgcn_exp2f(fmaf(st[jt][0], LOG2E, negml));
            const float p1 = __builtin_amdgcn_exp2f(fmaf(st[jt][1], LOG2E, negml));
            const float p2 = __builtin_amdgcn_exp2f(fmaf(st[jt][2], LOG2E, negml));
            const float p3 = __builtin_amdgcn_exp2f(fmaf(st[jt][3], LOG2E, negml));
            ps += (p0 + p1) + (p2 + p3);
            // pack to bf16 (round-half-up) and store P[i=li][16jt+4quad+r]
            uint2 pw;
            pw.x = __builtin_amdgcn_perm(__float_as_uint(p1) + 0x8000u,
                                         __float_as_uint(p0) + 0x8000u, 0x07060302u);
            pw.y = __builtin_amdgcn_perm(__float_as_uint(p3) + 0x8000u,
                                         __float_as_uint(p2) + 0x8000u, 0x07060302u);
            *(uint2*)&Ps[li][16 * jt + 4 * quad] = pw;
        }
        ps += __shfl_xor(ps, 16);
        ps += __shfl_xor(ps, 32);

        const float alpha = __builtin_amdgcn_exp2f(fmaf(m_run, LOG2E, negml)); // first tile: 0
        l_run = fmaf(l_run, alpha, ps);
        m_run = mnew;

        // O-rescale: O rows i=4*quad+r; alpha lives at lane i (quad 0 copy)
        float af[4];
        #pragma unroll
        for (int r = 0; r < 4; ++r) af[r] = __shfl(alpha, 4 * quad + r);
        #pragma unroll
        for (int r = 0; r < 4; ++r) { o0[r] *= af[r]; o1[r] *= af[r]; }

        // P in A-layout: lane reads P[i=li][32c + quad*8 + jj]
        const bf16x8 pa0 = *(const bf16x8*)&Ps[li][8 * quad];
        const bf16x8 pa1 = *(const bf16x8*)&Ps[li][32 + 8 * quad];
        o0 = __builtin_amdgcn_mfma_f32_16x16x32_bf16(pa0, vf[0], o0, 0, 0, 0);
        o0 = __builtin_amdgcn_mfma_f32_16x16x32_bf16(pa1, vf[2], o0, 0, 0, 0);
        o1 = __builtin_amdgcn_mfma_f32_16x16x32_bf16(pa0, vf[1], o1, 0, 0, 0);
        o1 = __builtin_amdgcn_mfma_f32_16x16x32_bf16(pa1, vf[3], o1, 0, 0, 0);
    };

    LOAD_TILE(kf0, vf0, 0);
    for (int kt = 0; kt < SEQ / 64; kt += 2) {
        if (kt + 1 < SEQ / 64) LOAD_TILE(kf1, vf1, (kt + 1) * 64);
        compute_tile(kf0, vf0);
        if (kt + 1 < SEQ / 64) {
            if (kt + 2 < SEQ / 64) LOAD_TILE(kf0, vf0, (kt + 2) * 64);
            compute_tile(kf1, vf1);
        }
    }
#undef LOAD_TILE

    // epilogue: O[i][p] / l[i], write ao[b][s][h][p] fp32
    float linv[4];
    #pragma unroll
    for (int r = 0; r < 4; ++r) linv[r] = 1.0f / __shfl(l_run, 4 * quad + r);
    #pragma unroll
    for (int r = 0; r < 4; ++r) {
        const int s = q0 + 4 * quad + r;
        float* row = ao + ((size_t)(b * SEQ + s)) * EMBED + h * PDIM;
        row[li]      = o0[r] * linv[r];
        row[16 + li] = o1[r] * linv[r];
    }
}

// ---------------------------------------------------------------------------
// Kernel 3: output projection (fp32).  out = ao[N,E] @ Wo + bo.
// ---------------------------------------------------------------------------
__global__ __launch_bounds__(256) void out_proj_kernel(
    const float* __restrict__ a, const float* __restrict__ Wo,
    const float* __restrict__ bo, float* __restrict__ out)
{
    const int r0 = blockIdx.x * 64;
    const int c0 = blockIdx.y * 64;
    const int t  = threadIdx.x;
    const int tx = t & 15, ty = t >> 4;

    __shared__ float AsT[32][68];
    __shared__ float Bs [32][68];

    float acc[4][4] = {};

    for (int k0 = 0; k0 < EMBED; k0 += 32) {
        {
            const int i  = t >> 3;
            const int kb = (t & 7) << 2;
            #pragma unroll
            for (int rep = 0; rep < 2; ++rep) {
                const int row = i + rep * 32;
                const float4 val = *(const float4*)&a[(size_t)(r0 + row) * EMBED + k0 + kb];
                AsT[kb + 0][row] = val.x; AsT[kb + 1][row] = val.y;
                AsT[kb + 2][row] = val.z; AsT[kb + 3][row] = val.w;
            }
            const int kk = t >> 4;
            const int cb = (t & 15) << 2;
            #pragma unroll
            for (int rep = 0; rep < 2; ++rep) {
                const int kkk = kk + rep * 16;
                *(float4*)&Bs[kkk][cb] =
                    *(const float4*)&Wo[(size_t)(k0 + kkk) * EMBED + c0 + cb];
            }
        }
        __syncthreads();
        #pragma unroll
        for (int kk = 0; kk < 32; ++kk) {
            const float4 av  = *(const float4*)&AsT[kk][ty << 2];
            const float4 bv4 = *(const float4*)&Bs [kk][tx << 2];
            const float aa[4] = {av.x, av.y, av.z, av.w};
            const float bb[4] = {bv4.x, bv4.y, bv4.z, bv4.w};
            #pragma unroll
            for (int rr = 0; rr < 4; ++rr)
                #pragma unroll
                for (int cc = 0; cc < 4; ++cc)
                    acc[rr][cc] += aa[rr] * bb[cc];
        }
        __syncthreads();
    }

    const int cbase = c0 + (tx << 2);
    const float4 bb = *(const float4*)&bo[cbase];
    #pragma unroll
    for (int rr = 0; rr < 4; ++rr) {
        const int n = r0 + (ty << 2) + rr;
        float4 val;
        val.x = acc[rr][0] + bb.x; val.y = acc[rr][1] + bb.y;
        val.z = acc[rr][2] + bb.z; val.w = acc[rr][3] + bb.w;
        *(float4*)&out[(size_t)n * EMBED + cbase] = val;
    }
}

// ---------------------------------------------------------------------------
extern "C" void kernel_launch(void* const* d_in, const int* in_sizes, int n_in,
                              void* d_out, int out_size, void* d_ws, size_t ws_size,
                              hipStream_t stream)
{
    const float* x  = (const float*)d_in[0];
    const float* Wq = (const float*)d_in[1];
    const float* bq = (const float*)d_in[2];
    const float* Wk = (const float*)d_in[3];
    const float* bk = (const float*)d_in[4];
    const float* Wv = (const float*)d_in[5];
    const float* bv = (const float*)d_in[6];
    const float* Wo = (const float*)d_in[7];
    const float* bo = (const float*)d_in[8];
    float* out = (float*)d_out;

    float*    ao  = (float*)d_ws;                                   // [b][s][h][p] fp32
    ushort_t* qb  = (ushort_t*)((char*)d_ws + (size_t)NTOK * EMBED * 4);
    ushort_t* kbf = qb  + (size_t)NTOK * EMBED;
    ushort_t* vtb = kbf + (size_t)NTOK * EMBED;                     // V^T [b][h][p][s]

    qkv_proj_kernel<<<dim3(NTOK / 64, EMBED / 64, 3), 256, 0, stream>>>(
        x, Wq, bq, Wk, bk, Wv, bv, qb, kbf, vtb);
    attn_kernel<<<dim3(SEQ / 16, BATCH * HEADS), 64, 0, stream>>>(
        qb, kbf, vtb, ao);
    out_proj_kernel<<<dim3(NTOK / 64, EMBED / 64), 256, 0, stream>>>(
        ao, Wo, bo, out);
}

// Round 3
// 137.611 us; speedup vs baseline: 2.1949x; 1.0817x over previous
//
#include <hip/hip_runtime.h>
#include <math.h>

#define EMBED 256
#define HEADS 8
#define PDIM  32
#define BATCH 2
#define SEQ   1728            // 12*12*12
#define NTOK  (BATCH*SEQ)     // 3456
#define NE    (NTOK*EMBED)    // 884736
#define LOG2E 1.44269504088896f

typedef __attribute__((ext_vector_type(8))) __bf16 bf16x8;
typedef __attribute__((ext_vector_type(4))) float  f32x4;
typedef unsigned short ushort_t;

static __device__ __forceinline__ unsigned short f2bf_rne(float f) {
    union { float f; unsigned u; } x; x.f = f;
    unsigned r = x.u + 0x7fffu + ((x.u >> 16) & 1u);
    return (unsigned short)(r >> 16);
}
static __device__ __forceinline__ float bf2f(unsigned short h) {
    union { unsigned u; float f; } x; x.u = ((unsigned)h) << 16;
    return x.f;
}

// ---------------------------------------------------------------------------
// Convert x (fp32) -> bf16 hi + lo residual.  grid 864 x 256, 4 elems/thread.
// ---------------------------------------------------------------------------
__global__ __launch_bounds__(256) void convert_x_kernel(
    const float* __restrict__ x, ushort_t* __restrict__ xhi, ushort_t* __restrict__ xlo)
{
    const int i = (blockIdx.x * 256 + threadIdx.x) * 4;
    const float4 v = *(const float4*)&x[i];
    ushort4 h, l;
    h.x = f2bf_rne(v.x); l.x = f2bf_rne(v.x - bf2f(h.x));
    h.y = f2bf_rne(v.y); l.y = f2bf_rne(v.y - bf2f(h.y));
    h.z = f2bf_rne(v.z); l.z = f2bf_rne(v.z - bf2f(h.z));
    h.w = f2bf_rne(v.w); l.w = f2bf_rne(v.w - bf2f(h.w));
    *(ushort4*)&xhi[i] = h;
    *(ushort4*)&xlo[i] = l;
}

// ---------------------------------------------------------------------------
// Convert + transpose the 4 weight matrices: W[k][n] fp32 -> WT_{hi,lo}[n][k]
// bf16, packed [mat][256][256].  grid (4 kt, 4 nt, 4 mat) x 256.
// ---------------------------------------------------------------------------
__global__ __launch_bounds__(256) void convert_w_kernel(
    const float* __restrict__ Wq, const float* __restrict__ Wk,
    const float* __restrict__ Wv, const float* __restrict__ Wo,
    ushort_t* __restrict__ wthi, ushort_t* __restrict__ wtlo)
{
    const int mat = blockIdx.z;
    const float* __restrict__ W = (mat == 0) ? Wq : (mat == 1) ? Wk : (mat == 2) ? Wv : Wo;
    const int k0 = blockIdx.x * 64, n0 = blockIdx.y * 64;
    const int t = threadIdx.x;

    __shared__ float Ws[64][68];
    {
        const int rr = t >> 4, cc = (t & 15) << 2;
        #pragma unroll
        for (int rep = 0; rep < 4; ++rep) {
            const int row = rr + rep * 16;
            *(float4*)&Ws[row][cc] = *(const float4*)&W[(size_t)(k0 + row) * EMBED + n0 + cc];
        }
    }
    __syncthreads();

    const int nl = t & 63;          // local n
    const int kc = (t >> 6) << 4;   // local k chunk base (0,16,32,48)
    ushort_t hv[16], lv[16];
    #pragma unroll
    for (int kk = 0; kk < 16; ++kk) {
        const float v = Ws[kc + kk][nl];
        hv[kk] = f2bf_rne(v);
        lv[kk] = f2bf_rne(v - bf2f(hv[kk]));
    }
    ushort_t* dh = wthi + (size_t)mat * 65536 + (size_t)(n0 + nl) * EMBED + k0 + kc;
    ushort_t* dl = wtlo + (size_t)mat * 65536 + (size_t)(n0 + nl) * EMBED + k0 + kc;
    #pragma unroll
    for (int c = 0; c < 4; ++c) {
        *(ushort4*)&dh[c * 4] = *(ushort4*)&hv[c * 4];
        *(ushort4*)&dl[c * 4] = *(ushort4*)&lv[c * 4];
    }
}

// ---------------------------------------------------------------------------
// QKV projection, bf16 MFMA with hi/lo split (~fp32 accuracy).
// grid (54, 8, 3), block 64 (1 wave).  Wave tile 64(M) x 32(N), K=256.
// A,B fragments straight from global (L2-hot), no LDS.
// Q,K -> [b][h][s][p] bf16;  V -> [b][h][p][s] bf16 (transposed).
// ---------------------------------------------------------------------------
__global__ __launch_bounds__(64) void qkv_gemm_kernel(
    const ushort_t* __restrict__ xhi, const ushort_t* __restrict__ xlo,
    const ushort_t* __restrict__ wthi, const ushort_t* __restrict__ wtlo,
    const float* __restrict__ bq, const float* __restrict__ bk, const float* __restrict__ bv,
    ushort_t* __restrict__ qo, ushort_t* __restrict__ ko, ushort_t* __restrict__ vt)
{
    const int lane = threadIdx.x, li = lane & 15, quad = lane >> 4;
    const int m0 = blockIdx.x * 64, n0 = blockIdx.y * 32, z = blockIdx.z;

    const ushort_t* aph = xhi + (size_t)(m0 + li) * EMBED + quad * 8;
    const ushort_t* apl = xlo + (size_t)(m0 + li) * EMBED + quad * 8;
    const ushort_t* bph = wthi + (size_t)z * 65536 + (size_t)(n0 + li) * EMBED + quad * 8;
    const ushort_t* bpl = wtlo + (size_t)z * 65536 + (size_t)(n0 + li) * EMBED + quad * 8;

    f32x4 acc[4][2];
    #pragma unroll
    for (int mt = 0; mt < 4; ++mt)
        #pragma unroll
        for (int nt = 0; nt < 2; ++nt)
            acc[mt][nt] = (f32x4){0.f, 0.f, 0.f, 0.f};

    #pragma unroll 2
    for (int k0 = 0; k0 < EMBED; k0 += 32) {
        bf16x8 ah[4], al[4], bh[2], bl[2];
        #pragma unroll
        for (int mt = 0; mt < 4; ++mt) {
            ah[mt] = *(const bf16x8*)(aph + (size_t)mt * 16 * EMBED + k0);
            al[mt] = *(const bf16x8*)(apl + (size_t)mt * 16 * EMBED + k0);
        }
        #pragma unroll
        for (int nt = 0; nt < 2; ++nt) {
            bh[nt] = *(const bf16x8*)(bph + (size_t)nt * 16 * EMBED + k0);
            bl[nt] = *(const bf16x8*)(bpl + (size_t)nt * 16 * EMBED + k0);
        }
        #pragma unroll
        for (int mt = 0; mt < 4; ++mt)
            #pragma unroll
            for (int nt = 0; nt < 2; ++nt) {
                acc[mt][nt] = __builtin_amdgcn_mfma_f32_16x16x32_bf16(ah[mt], bh[nt], acc[mt][nt], 0, 0, 0);
                acc[mt][nt] = __builtin_amdgcn_mfma_f32_16x16x32_bf16(al[mt], bh[nt], acc[mt][nt], 0, 0, 0);
                acc[mt][nt] = __builtin_amdgcn_mfma_f32_16x16x32_bf16(ah[mt], bl[nt], acc[mt][nt], 0, 0, 0);
            }
    }

    const int b = m0 / SEQ;
    const int sbase = m0 - b * SEQ;   // 64-row block never straddles batch (SEQ%64==0)

    if (z <= 1) {
        ushort_t* __restrict__ dst = z ? ko : qo;
        const float* __restrict__ bias = z ? bk : bq;
        #pragma unroll
        for (int nt = 0; nt < 2; ++nt) {
            const int gcol = n0 + nt * 16 + li;
            const int h = gcol >> 5, p = gcol & 31;
            const float bb = bias[gcol];
            ushort_t* base = dst + ((size_t)(b * HEADS + h) * SEQ) * PDIM + p;
            #pragma unroll
            for (int mt = 0; mt < 4; ++mt)
                #pragma unroll
                for (int r = 0; r < 4; ++r) {
                    const int s = sbase + mt * 16 + quad * 4 + r;
                    base[(size_t)s * PDIM] = f2bf_rne(acc[mt][nt][r] + bb);
                }
        }
    } else {
        #pragma unroll
        for (int nt = 0; nt < 2; ++nt) {
            const int gcol = n0 + nt * 16 + li;
            const int h = gcol >> 5, p = gcol & 31;
            const float bb = bv[gcol];
            ushort_t* base = vt + ((size_t)(b * HEADS + h) * PDIM + p) * SEQ;
            #pragma unroll
            for (int mt = 0; mt < 4; ++mt) {
                const int s0 = sbase + mt * 16 + quad * 4;
                ushort4 w;
                w.x = f2bf_rne(acc[mt][nt][0] + bb);
                w.y = f2bf_rne(acc[mt][nt][1] + bb);
                w.z = f2bf_rne(acc[mt][nt][2] + bb);
                w.w = f2bf_rne(acc[mt][nt][3] + bb);
                *(ushort4*)&base[s0] = w;
            }
        }
    }
}

// ---------------------------------------------------------------------------
// Kernel: flash attention, bf16 MFMA.  One wave per 16 query rows.
// grid (SEQ/16, B*H), block 64.  Epilogue now writes ao in bf16.
// ---------------------------------------------------------------------------
__global__ __launch_bounds__(64) void attn_kernel(
    const ushort_t* __restrict__ q, const ushort_t* __restrict__ k,
    const ushort_t* __restrict__ vt, ushort_t* __restrict__ aob)
{
    const int lane = threadIdx.x;
    const int li   = lane & 15;
    const int quad = lane >> 4;
    const int bh = blockIdx.y;
    const int b  = bh >> 3, h = bh & 7;
    const int q0 = blockIdx.x * 16;

    const ushort_t* __restrict__ qb = q  + (size_t)bh * SEQ * PDIM;
    const ushort_t* __restrict__ kb = k  + (size_t)bh * SEQ * PDIM;
    const ushort_t* __restrict__ vb = vt + (size_t)bh * PDIM * SEQ;

    __shared__ ushort_t Ps[16][72];

    const bf16x8 qfrag = *(const bf16x8*)(qb + (size_t)(q0 + li) * PDIM + quad * 8);

    const ushort_t* kptr = kb + (size_t)li * PDIM + quad * 8;
    const ushort_t* vptr = vb + (size_t)li * SEQ + quad * 8;

    f32x4 o0 = {0.f, 0.f, 0.f, 0.f};
    f32x4 o1 = {0.f, 0.f, 0.f, 0.f};
    float m_run = -__builtin_inff(), l_run = 0.f;

    bf16x8 kf0[4], vf0[4], kf1[4], vf1[4];

#define LOAD_TILE(KF, VF, J0) do {                                           \
        const ushort_t* kp = kptr + (size_t)(J0) * PDIM;                     \
        KF[0] = *(const bf16x8*)(kp);                                        \
        KF[1] = *(const bf16x8*)(kp + 16 * PDIM);                            \
        KF[2] = *(const bf16x8*)(kp + 32 * PDIM);                            \
        KF[3] = *(const bf16x8*)(kp + 48 * PDIM);                            \
        const ushort_t* vp = vptr + (J0);                                    \
        VF[0] = *(const bf16x8*)(vp);                                        \
        VF[1] = *(const bf16x8*)(vp + 16 * SEQ);                             \
        VF[2] = *(const bf16x8*)(vp + 32);                                   \
        VF[3] = *(const bf16x8*)(vp + 32 + 16 * SEQ);                        \
    } while (0)

    auto compute_tile = [&](const bf16x8* kf, const bf16x8* vf) {
        const f32x4 zero = {0.f, 0.f, 0.f, 0.f};
        f32x4 st[4];
        #pragma unroll
        for (int jt = 0; jt < 4; ++jt)
            st[jt] = __builtin_amdgcn_mfma_f32_16x16x32_bf16(kf[jt], qfrag, zero, 0, 0, 0);

        float tm = st[0][0];
        #pragma unroll
        for (int jt = 0; jt < 4; ++jt)
            #pragma unroll
            for (int r = 0; r < 4; ++r) tm = fmaxf(tm, st[jt][r]);
        tm = fmaxf(tm, __shfl_xor(tm, 16));
        tm = fmaxf(tm, __shfl_xor(tm, 32));
        const float mnew  = fmaxf(m_run, tm);
        const float negml = -(mnew * LOG2E);

        float ps = 0.f;
        #pragma unroll
        for (int jt = 0; jt < 4; ++jt) {
            const float p0 = __builtin_amdgcn_exp2f(fmaf(st[jt][0], LOG2E, negml));
            const float p1 = __builtin_amdgcn_exp2f(fmaf(st[jt][1], LOG2E, negml));
            const float p2 = __builtin_amdgcn_exp2f(fmaf(st[jt][2], LOG2E, negml));
            const float p3 = __builtin_amdgcn_exp2f(fmaf(st[jt][3], LOG2E, negml));
            ps += (p0 + p1) + (p2 + p3);
            uint2 pw;
            pw.x = __builtin_amdgcn_perm(__float_as_uint(p1) + 0x8000u,
                                         __float_as_uint(p0) + 0x8000u, 0x07060302u);
            pw.y = __builtin_amdgcn_perm(__float_as_uint(p3) + 0x8000u,
                                         __float_as_uint(p2) + 0x8000u, 0x07060302u);
            *(uint2*)&Ps[li][16 * jt + 4 * quad] = pw;
        }
        ps += __shfl_xor(ps, 16);
        ps += __shfl_xor(ps, 32);

        const float alpha = __builtin_amdgcn_exp2f(fmaf(m_run, LOG2E, negml));
        l_run = fmaf(l_run, alpha, ps);
        m_run = mnew;

        float af[4];
        #pragma unroll
        for (int r = 0; r < 4; ++r) af[r] = __shfl(alpha, 4 * quad + r);
        #pragma unroll
        for (int r = 0; r < 4; ++r) { o0[r] *= af[r]; o1[r] *= af[r]; }

        const bf16x8 pa0 = *(const bf16x8*)&Ps[li][8 * quad];
        const bf16x8 pa1 = *(const bf16x8*)&Ps[li][32 + 8 * quad];
        o0 = __builtin_amdgcn_mfma_f32_16x16x32_bf16(pa0, vf[0], o0, 0, 0, 0);
        o0 = __builtin_amdgcn_mfma_f32_16x16x32_bf16(pa1, vf[2], o0, 0, 0, 0);
        o1 = __builtin_amdgcn_mfma_f32_16x16x32_bf16(pa0, vf[1], o1, 0, 0, 0);
        o1 = __builtin_amdgcn_mfma_f32_16x16x32_bf16(pa1, vf[3], o1, 0, 0, 0);
    };

    LOAD_TILE(kf0, vf0, 0);
    for (int kt = 0; kt < SEQ / 64; kt += 2) {
        if (kt + 1 < SEQ / 64) LOAD_TILE(kf1, vf1, (kt + 1) * 64);
        compute_tile(kf0, vf0);
        if (kt + 1 < SEQ / 64) {
            if (kt + 2 < SEQ / 64) LOAD_TILE(kf0, vf0, (kt + 2) * 64);
            compute_tile(kf1, vf1);
        }
    }
#undef LOAD_TILE

    float linv[4];
    #pragma unroll
    for (int r = 0; r < 4; ++r) linv[r] = 1.0f / __shfl(l_run, 4 * quad + r);
    #pragma unroll
    for (int r = 0; r < 4; ++r) {
        const int s = q0 + 4 * quad + r;
        ushort_t* row = aob + ((size_t)(b * SEQ + s)) * EMBED + h * PDIM;
        row[li]      = f2bf_rne(o0[r] * linv[r]);
        row[16 + li] = f2bf_rne(o1[r] * linv[r]);
    }
}

// ---------------------------------------------------------------------------
// Output projection, plain bf16 MFMA.  grid (54, 16), block 64.
// Wave tile 64(M) x 16(N), K=256.  out fp32.
// ---------------------------------------------------------------------------
__global__ __launch_bounds__(64) void out_gemm_kernel(
    const ushort_t* __restrict__ a, const ushort_t* __restrict__ wto,
    const float* __restrict__ bo, float* __restrict__ out)
{
    const int lane = threadIdx.x, li = lane & 15, quad = lane >> 4;
    const int m0 = blockIdx.x * 64, n0 = blockIdx.y * 16;

    const ushort_t* aph = a + (size_t)(m0 + li) * EMBED + quad * 8;
    const ushort_t* bph = wto + (size_t)(n0 + li) * EMBED + quad * 8;

    f32x4 acc[4];
    #pragma unroll
    for (int mt = 0; mt < 4; ++mt) acc[mt] = (f32x4){0.f, 0.f, 0.f, 0.f};

    #pragma unroll 2
    for (int k0 = 0; k0 < EMBED; k0 += 32) {
        bf16x8 ah[4];
        #pragma unroll
        for (int mt = 0; mt < 4; ++mt)
            ah[mt] = *(const bf16x8*)(aph + (size_t)mt * 16 * EMBED + k0);
        const bf16x8 bh = *(const bf16x8*)(bph + k0);
        #pragma unroll
        for (int mt = 0; mt < 4; ++mt)
            acc[mt] = __builtin_amdgcn_mfma_f32_16x16x32_bf16(ah[mt], bh, acc[mt], 0, 0, 0);
    }

    const int gcol = n0 + li;
    const float bb = bo[gcol];
    #pragma unroll
    for (int mt = 0; mt < 4; ++mt)
        #pragma unroll
        for (int r = 0; r < 4; ++r) {
            const int row = m0 + mt * 16 + quad * 4 + r;
            out[(size_t)row * EMBED + gcol] = acc[mt][r] + bb;
        }
}

// ---------------------------------------------------------------------------
extern "C" void kernel_launch(void* const* d_in, const int* in_sizes, int n_in,
                              void* d_out, int out_size, void* d_ws, size_t ws_size,
                              hipStream_t stream)
{
    const float* x  = (const float*)d_in[0];
    const float* Wq = (const float*)d_in[1];
    const float* bq = (const float*)d_in[2];
    const float* Wk = (const float*)d_in[3];
    const float* bk = (const float*)d_in[4];
    const float* Wv = (const float*)d_in[5];
    const float* bv = (const float*)d_in[6];
    const float* Wo = (const float*)d_in[7];
    const float* bo = (const float*)d_in[8];
    float* out = (float*)d_out;

    ushort_t* ws   = (ushort_t*)d_ws;
    ushort_t* xhi  = ws;
    ushort_t* xlo  = xhi + (size_t)NE;
    ushort_t* wthi = xlo + (size_t)NE;          // [4][256][256]
    ushort_t* wtlo = wthi + 4 * 65536;
    ushort_t* qb   = wtlo + 4 * 65536;          // [b][h][s][p]
    ushort_t* kb   = qb + (size_t)NE;
    ushort_t* vt   = kb + (size_t)NE;           // [b][h][p][s]
    ushort_t* aob  = vt + (size_t)NE;           // [b][s][h][p] bf16

    convert_x_kernel<<<dim3(NE / 1024), 256, 0, stream>>>(x, xhi, xlo);
    convert_w_kernel<<<dim3(4, 4, 4), 256, 0, stream>>>(Wq, Wk, Wv, Wo, wthi, wtlo);
    qkv_gemm_kernel<<<dim3(NTOK / 64, 8, 3), 64, 0, stream>>>(
        xhi, xlo, wthi, wtlo, bq, bk, bv, qb, kb, vt);
    attn_kernel<<<dim3(SEQ / 16, BATCH * HEADS), 64, 0, stream>>>(qb, kb, vt, aob);
    out_gemm_kernel<<<dim3(NTOK / 64, 16), 64, 0, stream>>>(
        aob, wthi + 3 * 65536, bo, out);
}

// Round 4
// 136.497 us; speedup vs baseline: 2.2128x; 1.0082x over previous
//
#include <hip/hip_runtime.h>
#include <math.h>

#define EMBED 256
#define HEADS 8
#define PDIM  32
#define BATCH 2
#define SEQ   1728            // 12*12*12
#define NTOK  (BATCH*SEQ)     // 3456
#define NE    (NTOK*EMBED)    // 884736
#define LOG2E 1.44269504088896f

typedef __attribute__((ext_vector_type(8))) __bf16 bf16x8;
typedef __attribute__((ext_vector_type(4))) float  f32x4;
typedef unsigned short ushort_t;
typedef unsigned int   uint_t;

static __device__ __forceinline__ unsigned short f2bf_rne(float f) {
    union { float f; unsigned u; } x; x.f = f;
    unsigned r = x.u + 0x7fffu + ((x.u >> 16) & 1u);
    return (unsigned short)(r >> 16);
}
union v8cast { uint4 u; bf16x8 v; };

// split 8 floats into bf16 hi (round-half-up) + bf16 lo residual, packed
static __device__ __forceinline__ void cvt8_hilo(const float f[8], bf16x8& hi, bf16x8& lo) {
    uint4 ph, pl;
    uint_t* phv = (uint_t*)&ph; uint_t* plv = (uint_t*)&pl;
    #pragma unroll
    for (int j = 0; j < 4; ++j) {
        const float f0 = f[2 * j], f1 = f[2 * j + 1];
        const uint_t u0 = __float_as_uint(f0) + 0x8000u;
        const uint_t u1 = __float_as_uint(f1) + 0x8000u;
        phv[j] = __builtin_amdgcn_perm(u1, u0, 0x07060302u);
        const float l0 = f0 - __uint_as_float(u0 & 0xFFFF0000u);
        const float l1 = f1 - __uint_as_float(u1 & 0xFFFF0000u);
        plv[j] = __builtin_amdgcn_perm(__float_as_uint(l1) + 0x8000u,
                                       __float_as_uint(l0) + 0x8000u, 0x07060302u);
    }
    v8cast ch; ch.u = ph; hi = ch.v;
    v8cast cl; cl.u = pl; lo = cl.v;
}

// ---------------------------------------------------------------------------
// Kernel 1: QKV projection, fused fp32->bf16 hi/lo conversion + MFMA.
// grid (216, 8, 3) x 64 (1 wave).  Wave tile 16(M) x 32(N), K=256.
// A from x fp32 (contiguous), B from W fp32 (strided dwords, L2-hot).
// Q,K -> [b][h][s][p] bf16;  V -> [b][h][p][s] bf16 (transposed).
// ---------------------------------------------------------------------------
__global__ __launch_bounds__(64) void qkv_gemm_kernel(
    const float* __restrict__ x,
    const float* __restrict__ Wq, const float* __restrict__ bq,
    const float* __restrict__ Wk, const float* __restrict__ bk,
    const float* __restrict__ Wv, const float* __restrict__ bv,
    ushort_t* __restrict__ qo, ushort_t* __restrict__ ko, ushort_t* __restrict__ vt)
{
    const int lane = threadIdx.x, li = lane & 15, quad = lane >> 4;
    const int m0 = blockIdx.x * 16, n0 = blockIdx.y * 32, z = blockIdx.z;
    const float* __restrict__ W    = (z == 0) ? Wq : (z == 1) ? Wk : Wv;
    const float* __restrict__ bias = (z == 0) ? bq : (z == 1) ? bk : bv;

    const float* ap = x + (size_t)(m0 + li) * EMBED + quad * 8;

    f32x4 acc[2];
    acc[0] = (f32x4){0.f, 0.f, 0.f, 0.f};
    acc[1] = (f32x4){0.f, 0.f, 0.f, 0.f};

    #pragma unroll
    for (int k0 = 0; k0 < EMBED; k0 += 32) {
        // A fragment: 8 contiguous fp32
        float af[8];
        *(float4*)&af[0] = *(const float4*)(ap + k0);
        *(float4*)&af[4] = *(const float4*)(ap + k0 + 4);
        bf16x8 ah, al;
        cvt8_hilo(af, ah, al);

        // B fragments: W^T[n0+nt*16+li][k0+quad*8+jj] = W[k][n], strided dwords
        bf16x8 bh[2], bl[2];
        #pragma unroll
        for (int nt = 0; nt < 2; ++nt) {
            const int n = n0 + nt * 16 + li;
            const float* wp = W + (size_t)(k0 + quad * 8) * EMBED + n;
            float bf[8];
            #pragma unroll
            for (int jj = 0; jj < 8; ++jj) bf[jj] = wp[(size_t)jj * EMBED];
            cvt8_hilo(bf, bh[nt], bl[nt]);
        }
        #pragma unroll
        for (int nt = 0; nt < 2; ++nt) {
            acc[nt] = __builtin_amdgcn_mfma_f32_16x16x32_bf16(ah, bh[nt], acc[nt], 0, 0, 0);
            acc[nt] = __builtin_amdgcn_mfma_f32_16x16x32_bf16(al, bh[nt], acc[nt], 0, 0, 0);
            acc[nt] = __builtin_amdgcn_mfma_f32_16x16x32_bf16(ah, bl[nt], acc[nt], 0, 0, 0);
        }
    }

    const int b = m0 / SEQ;          // 16-row tile never straddles batch
    const int sbase = m0 - b * SEQ;

    if (z <= 1) {
        ushort_t* __restrict__ dst = z ? ko : qo;
        #pragma unroll
        for (int nt = 0; nt < 2; ++nt) {
            const int gcol = n0 + nt * 16 + li;
            const int h = gcol >> 5, p = gcol & 31;
            const float bb = bias[gcol];
            ushort_t* base = dst + ((size_t)(b * HEADS + h) * SEQ) * PDIM + p;
            #pragma unroll
            for (int r = 0; r < 4; ++r) {
                const int s = sbase + quad * 4 + r;
                base[(size_t)s * PDIM] = f2bf_rne(acc[nt][r] + bb);
            }
        }
    } else {
        #pragma unroll
        for (int nt = 0; nt < 2; ++nt) {
            const int gcol = n0 + nt * 16 + li;
            const int h = gcol >> 5, p = gcol & 31;
            const float bb = bias[gcol];
            ushort_t* base = vt + ((size_t)(b * HEADS + h) * PDIM + p) * SEQ;
            const int s0 = sbase + quad * 4;
            ushort4 w;
            w.x = f2bf_rne(acc[nt][0] + bb);
            w.y = f2bf_rne(acc[nt][1] + bb);
            w.z = f2bf_rne(acc[nt][2] + bb);
            w.w = f2bf_rne(acc[nt][3] + bb);
            *(ushort4*)&base[s0] = w;
        }
    }
}

// ---------------------------------------------------------------------------
// Kernel 2: flash attention, bf16 MFMA, split-K=2.
// grid (54, 16) x 256 (4 waves).  Wave w: pair p=w>>1 (q-tile 2*bx+p),
// chunk c=w&1 (c=0: k-tiles [0,14), c=1: [14,27)).  Pair merges (m,l,O)
// through LDS; wave c==0 writes the combined output (bf16 [b][s][h][p]).
// ---------------------------------------------------------------------------
__global__ __launch_bounds__(256) void attn_kernel(
    const ushort_t* __restrict__ q, const ushort_t* __restrict__ k,
    const ushort_t* __restrict__ vt, ushort_t* __restrict__ aob)
{
    const int t    = threadIdx.x;
    const int lane = t & 63;
    const int li   = lane & 15;
    const int quad = lane >> 4;
    const int w    = t >> 6;
    const int pr   = w >> 1;          // pair within block
    const int c    = w & 1;           // K-chunk
    const int bh = blockIdx.y;
    const int b  = bh >> 3, h = bh & 7;
    const int q0 = (blockIdx.x * 2 + pr) * 16;

    const ushort_t* __restrict__ qb = q  + (size_t)bh * SEQ * PDIM;
    const ushort_t* __restrict__ kb = k  + (size_t)bh * SEQ * PDIM;
    const ushort_t* __restrict__ vb = vt + (size_t)bh * PDIM * SEQ;

    __shared__ ushort_t Ps[4][16][72];
    __shared__ float OS[2][16][32];
    __shared__ float mS[2][16], lS[2][16];

    const bf16x8 qfrag = *(const bf16x8*)(qb + (size_t)(q0 + li) * PDIM + quad * 8);

    const ushort_t* kptr = kb + (size_t)li * PDIM + quad * 8;
    const ushort_t* vptr = vb + (size_t)li * SEQ + quad * 8;

    f32x4 o0 = {0.f, 0.f, 0.f, 0.f};
    f32x4 o1 = {0.f, 0.f, 0.f, 0.f};
    float m_run = -__builtin_inff(), l_run = 0.f;

    bf16x8 kf0[4], vf0[4], kf1[4], vf1[4];

#define LOAD_TILE(KF, VF, J0) do {                                           \
        const ushort_t* kp = kptr + (size_t)(J0) * PDIM;                     \
        KF[0] = *(const bf16x8*)(kp);                                        \
        KF[1] = *(const bf16x8*)(kp + 16 * PDIM);                            \
        KF[2] = *(const bf16x8*)(kp + 32 * PDIM);                            \
        KF[3] = *(const bf16x8*)(kp + 48 * PDIM);                            \
        const ushort_t* vp = vptr + (J0);                                    \
        VF[0] = *(const bf16x8*)(vp);                                        \
        VF[1] = *(const bf16x8*)(vp + 16 * SEQ);                             \
        VF[2] = *(const bf16x8*)(vp + 32);                                   \
        VF[3] = *(const bf16x8*)(vp + 32 + 16 * SEQ);                        \
    } while (0)

    auto compute_tile = [&](const bf16x8* kf, const bf16x8* vf) {
        const f32x4 zero = {0.f, 0.f, 0.f, 0.f};
        f32x4 st[4];
        #pragma unroll
        for (int jt = 0; jt < 4; ++jt)
            st[jt] = __builtin_amdgcn_mfma_f32_16x16x32_bf16(kf[jt], qfrag, zero, 0, 0, 0);

        float tm = st[0][0];
        #pragma unroll
        for (int jt = 0; jt < 4; ++jt)
            #pragma unroll
            for (int r = 0; r < 4; ++r) tm = fmaxf(tm, st[jt][r]);
        tm = fmaxf(tm, __shfl_xor(tm, 16));
        tm = fmaxf(tm, __shfl_xor(tm, 32));
        const float mnew  = fmaxf(m_run, tm);
        const float negml = -(mnew * LOG2E);

        float ps = 0.f;
        #pragma unroll
        for (int jt = 0; jt < 4; ++jt) {
            const float p0 = __builtin_amdgcn_exp2f(fmaf(st[jt][0], LOG2E, negml));
            const float p1 = __builtin_amdgcn_exp2f(fmaf(st[jt][1], LOG2E, negml));
            const float p2 = __builtin_amdgcn_exp2f(fmaf(st[jt][2], LOG2E, negml));
            const float p3 = __builtin_amdgcn_exp2f(fmaf(st[jt][3], LOG2E, negml));
            ps += (p0 + p1) + (p2 + p3);
            uint2 pw;
            pw.x = __builtin_amdgcn_perm(__float_as_uint(p1) + 0x8000u,
                                         __float_as_uint(p0) + 0x8000u, 0x07060302u);
            pw.y = __builtin_amdgcn_perm(__float_as_uint(p3) + 0x8000u,
                                         __float_as_uint(p2) + 0x8000u, 0x07060302u);
            *(uint2*)&Ps[w][li][16 * jt + 4 * quad] = pw;
        }
        ps += __shfl_xor(ps, 16);
        ps += __shfl_xor(ps, 32);

        const float alpha = __builtin_amdgcn_exp2f(fmaf(m_run, LOG2E, negml));
        l_run = fmaf(l_run, alpha, ps);
        m_run = mnew;

        float af[4];
        #pragma unroll
        for (int r = 0; r < 4; ++r) af[r] = __shfl(alpha, 4 * quad + r);
        #pragma unroll
        for (int r = 0; r < 4; ++r) { o0[r] *= af[r]; o1[r] *= af[r]; }

        const bf16x8 pa0 = *(const bf16x8*)&Ps[w][li][8 * quad];
        const bf16x8 pa1 = *(const bf16x8*)&Ps[w][li][32 + 8 * quad];
        o0 = __builtin_amdgcn_mfma_f32_16x16x32_bf16(pa0, vf[0], o0, 0, 0, 0);
        o0 = __builtin_amdgcn_mfma_f32_16x16x32_bf16(pa1, vf[2], o0, 0, 0, 0);
        o1 = __builtin_amdgcn_mfma_f32_16x16x32_bf16(pa0, vf[1], o1, 0, 0, 0);
        o1 = __builtin_amdgcn_mfma_f32_16x16x32_bf16(pa1, vf[3], o1, 0, 0, 0);
    };

    const int jstart = c ? 896 : 0;      // c0: 14 tiles, c1: 13 tiles
    const int ntl    = c ? 13 : 14;

    LOAD_TILE(kf0, vf0, jstart);
    for (int kt = 0; kt < ntl; kt += 2) {
        if (kt + 1 < ntl) LOAD_TILE(kf1, vf1, jstart + (kt + 1) * 64);
        compute_tile(kf0, vf0);
        if (kt + 1 < ntl) {
            if (kt + 2 < ntl) LOAD_TILE(kf0, vf0, jstart + (kt + 2) * 64);
            compute_tile(kf1, vf1);
        }
    }
#undef LOAD_TILE

    // ---- pair merge ----
    if (c == 1) {
        if (quad == 0) { mS[pr][li] = m_run; lS[pr][li] = l_run; }
        #pragma unroll
        for (int r = 0; r < 4; ++r) {
            OS[pr][4 * quad + r][li]      = o0[r];
            OS[pr][4 * quad + r][16 + li] = o1[r];
        }
    }
    __syncthreads();
    if (c == 0) {
        const float m1 = mS[pr][li], l1 = lS[pr][li];
        const float M  = fmaxf(m_run, m1);
        const float a0 = __builtin_amdgcn_exp2f((m_run - M) * LOG2E);
        const float a1 = __builtin_amdgcn_exp2f((m1    - M) * LOG2E);
        const float lt = a0 * l_run + a1 * l1;
        #pragma unroll
        for (int r = 0; r < 4; ++r) {
            const int row = 4 * quad + r;
            const float af0  = __shfl(a0, row);
            const float af1  = __shfl(a1, row);
            const float linv = 1.0f / __shfl(lt, row);
            const float v0 = (af0 * o0[r] + af1 * OS[pr][row][li])      * linv;
            const float v1 = (af0 * o1[r] + af1 * OS[pr][row][16 + li]) * linv;
            const int s = q0 + row;
            ushort_t* orow = aob + ((size_t)(b * SEQ + s)) * EMBED + h * PDIM;
            orow[li]      = f2bf_rne(v0);
            orow[16 + li] = f2bf_rne(v1);
        }
    }
}

// ---------------------------------------------------------------------------
// Kernel 3: output projection, bf16 MFMA, fused Wo fp32->bf16 conversion.
// grid (216, 16) x 64.  Wave tile 16(M) x 16(N), K=256.  out fp32.
// ---------------------------------------------------------------------------
__global__ __launch_bounds__(64) void out_gemm_kernel(
    const ushort_t* __restrict__ a, const float* __restrict__ Wo,
    const float* __restrict__ bo, float* __restrict__ out)
{
    const int lane = threadIdx.x, li = lane & 15, quad = lane >> 4;
    const int m0 = blockIdx.x * 16, n0 = blockIdx.y * 16;

    const ushort_t* aph = a + (size_t)(m0 + li) * EMBED + quad * 8;

    f32x4 acc = {0.f, 0.f, 0.f, 0.f};

    #pragma unroll
    for (int k0 = 0; k0 < EMBED; k0 += 32) {
        const bf16x8 ah = *(const bf16x8*)(aph + k0);
        // B: Wo^T[n0+li][k0+quad*8+jj] from fp32, hi only
        const float* wp = Wo + (size_t)(k0 + quad * 8) * EMBED + n0 + li;
        uint4 pb;
        uint_t* pbv = (uint_t*)&pb;
        #pragma unroll
        for (int j = 0; j < 4; ++j) {
            const uint_t u0 = __float_as_uint(wp[(size_t)(2 * j) * EMBED])     + 0x8000u;
            const uint_t u1 = __float_as_uint(wp[(size_t)(2 * j + 1) * EMBED]) + 0x8000u;
            pbv[j] = __builtin_amdgcn_perm(u1, u0, 0x07060302u);
        }
        v8cast cb; cb.u = pb;
        acc = __builtin_amdgcn_mfma_f32_16x16x32_bf16(ah, cb.v, acc, 0, 0, 0);
    }

    const float bb = bo[n0 + li];
    #pragma unroll
    for (int r = 0; r < 4; ++r) {
        const int row = m0 + 4 * quad + r;
        out[(size_t)row * EMBED + n0 + li] = acc[r] + bb;
    }
}

// ---------------------------------------------------------------------------
extern "C" void kernel_launch(void* const* d_in, const int* in_sizes, int n_in,
                              void* d_out, int out_size, void* d_ws, size_t ws_size,
                              hipStream_t stream)
{
    const float* x  = (const float*)d_in[0];
    const float* Wq = (const float*)d_in[1];
    const float* bq = (const float*)d_in[2];
    const float* Wk = (const float*)d_in[3];
    const float* bk = (const float*)d_in[4];
    const float* Wv = (const float*)d_in[5];
    const float* bv = (const float*)d_in[6];
    const float* Wo = (const float*)d_in[7];
    const float* bo = (const float*)d_in[8];
    float* out = (float*)d_out;

    ushort_t* ws  = (ushort_t*)d_ws;
    ushort_t* qb  = ws;                      // [b][h][s][p] bf16
    ushort_t* kb  = qb + (size_t)NE;
    ushort_t* vt  = kb + (size_t)NE;         // [b][h][p][s] bf16
    ushort_t* aob = vt + (size_t)NE;         // [b][s][h][p] bf16

    qkv_gemm_kernel<<<dim3(NTOK / 16, 8, 3), 64, 0, stream>>>(
        x, Wq, bq, Wk, bk, Wv, bv, qb, kb, vt);
    attn_kernel<<<dim3(SEQ / 32, BATCH * HEADS), 256, 0, stream>>>(qb, kb, vt, aob);
    out_gemm_kernel<<<dim3(NTOK / 16, 16), 64, 0, stream>>>(aob, Wo, bo, out);
}

// Round 5
// 121.504 us; speedup vs baseline: 2.4858x; 1.1234x over previous
//
#include <hip/hip_runtime.h>
#include <math.h>

#define EMBED 256
#define HEADS 8
#define PDIM  32
#define BATCH 2
#define SEQ   1728            // 12*12*12
#define NTOK  (BATCH*SEQ)     // 3456
#define NE    (NTOK*EMBED)    // 884736
#define NKT   (SEQ/64)        // 27 key tiles
#define LOG2E 1.44269504088896f

typedef __attribute__((ext_vector_type(8))) __bf16 bf16x8;
typedef __attribute__((ext_vector_type(4))) float  f32x4;
typedef unsigned short ushort_t;
typedef unsigned int   uint_t;

static __device__ __forceinline__ unsigned short f2bf_rne(float f) {
    union { float f; unsigned u; } x; x.f = f;
    unsigned r = x.u + 0x7fffu + ((x.u >> 16) & 1u);
    return (unsigned short)(r >> 16);
}
union v8cast { uint4 u; bf16x8 v; };

// split 8 floats into bf16 hi (round-half-up) + bf16 lo residual, packed
static __device__ __forceinline__ void cvt8_hilo(const float f[8], bf16x8& hi, bf16x8& lo) {
    uint4 ph, pl;
    uint_t* phv = (uint_t*)&ph; uint_t* plv = (uint_t*)&pl;
    #pragma unroll
    for (int j = 0; j < 4; ++j) {
        const float f0 = f[2 * j], f1 = f[2 * j + 1];
        const uint_t u0 = __float_as_uint(f0) + 0x8000u;
        const uint_t u1 = __float_as_uint(f1) + 0x8000u;
        phv[j] = __builtin_amdgcn_perm(u1, u0, 0x07060302u);
        const float l0 = f0 - __uint_as_float(u0 & 0xFFFF0000u);
        const float l1 = f1 - __uint_as_float(u1 & 0xFFFF0000u);
        plv[j] = __builtin_amdgcn_perm(__float_as_uint(l1) + 0x8000u,
                                       __float_as_uint(l0) + 0x8000u, 0x07060302u);
    }
    v8cast ch; ch.u = ph; hi = ch.v;
    v8cast cl; cl.u = pl; lo = cl.v;
}

// ---------------------------------------------------------------------------
// Kernel 1: QKV projection, fused fp32->bf16 hi/lo conversion + MFMA.
// grid (54, 8, 3) x 64 (1 wave).  Wave tile 64(M) x 32(N), K=256.
// B panel read once per wave (M=64 amortizes it 4x vs R4's M=16).
// Q,K -> [b][h][s][p] bf16;  V -> [b][h][p][s] bf16 (transposed).
// ---------------------------------------------------------------------------
__global__ __launch_bounds__(64) void qkv_gemm_kernel(
    const float* __restrict__ x,
    const float* __restrict__ Wq, const float* __restrict__ bq,
    const float* __restrict__ Wk, const float* __restrict__ bk,
    const float* __restrict__ Wv, const float* __restrict__ bv,
    ushort_t* __restrict__ qo, ushort_t* __restrict__ ko, ushort_t* __restrict__ vt)
{
    const int lane = threadIdx.x, li = lane & 15, quad = lane >> 4;
    const int m0 = blockIdx.x * 64, n0 = blockIdx.y * 32, z = blockIdx.z;
    const float* __restrict__ W    = (z == 0) ? Wq : (z == 1) ? Wk : Wv;
    const float* __restrict__ bias = (z == 0) ? bq : (z == 1) ? bk : bv;

    const float* ap = x + (size_t)(m0 + li) * EMBED + quad * 8;

    f32x4 acc[4][2];
    #pragma unroll
    for (int mt = 0; mt < 4; ++mt)
        #pragma unroll
        for (int nt = 0; nt < 2; ++nt)
            acc[mt][nt] = (f32x4){0.f, 0.f, 0.f, 0.f};

    #pragma unroll 2
    for (int k0 = 0; k0 < EMBED; k0 += 32) {
        bf16x8 ah[4], al[4];
        #pragma unroll
        for (int mt = 0; mt < 4; ++mt) {
            float af[8];
            *(float4*)&af[0] = *(const float4*)(ap + (size_t)mt * 16 * EMBED + k0);
            *(float4*)&af[4] = *(const float4*)(ap + (size_t)mt * 16 * EMBED + k0 + 4);
            cvt8_hilo(af, ah[mt], al[mt]);
        }
        bf16x8 bh[2], bl[2];
        #pragma unroll
        for (int nt = 0; nt < 2; ++nt) {
            const int n = n0 + nt * 16 + li;
            const float* wp = W + (size_t)(k0 + quad * 8) * EMBED + n;
            float bf[8];
            #pragma unroll
            for (int jj = 0; jj < 8; ++jj) bf[jj] = wp[(size_t)jj * EMBED];
            cvt8_hilo(bf, bh[nt], bl[nt]);
        }
        #pragma unroll
        for (int mt = 0; mt < 4; ++mt)
            #pragma unroll
            for (int nt = 0; nt < 2; ++nt) {
                acc[mt][nt] = __builtin_amdgcn_mfma_f32_16x16x32_bf16(ah[mt], bh[nt], acc[mt][nt], 0, 0, 0);
                acc[mt][nt] = __builtin_amdgcn_mfma_f32_16x16x32_bf16(al[mt], bh[nt], acc[mt][nt], 0, 0, 0);
                acc[mt][nt] = __builtin_amdgcn_mfma_f32_16x16x32_bf16(ah[mt], bl[nt], acc[mt][nt], 0, 0, 0);
            }
    }

    const int b = m0 / SEQ;          // 64-row tile never straddles batch (SEQ%64==0)
    const int sbase = m0 - b * SEQ;

    if (z <= 1) {
        ushort_t* __restrict__ dst = z ? ko : qo;
        #pragma unroll
        for (int nt = 0; nt < 2; ++nt) {
            const int gcol = n0 + nt * 16 + li;
            const int h = gcol >> 5, p = gcol & 31;
            const float bb = bias[gcol];
            ushort_t* base = dst + ((size_t)(b * HEADS + h) * SEQ) * PDIM + p;
            #pragma unroll
            for (int mt = 0; mt < 4; ++mt)
                #pragma unroll
                for (int r = 0; r < 4; ++r) {
                    const int s = sbase + mt * 16 + quad * 4 + r;
                    base[(size_t)s * PDIM] = f2bf_rne(acc[mt][nt][r] + bb);
                }
        }
    } else {
        #pragma unroll
        for (int nt = 0; nt < 2; ++nt) {
            const int gcol = n0 + nt * 16 + li;
            const int h = gcol >> 5, p = gcol & 31;
            const float bb = bias[gcol];
            ushort_t* base = vt + ((size_t)(b * HEADS + h) * PDIM + p) * SEQ;
            #pragma unroll
            for (int mt = 0; mt < 4; ++mt) {
                const int s0 = sbase + mt * 16 + quad * 4;
                ushort4 w;
                w.x = f2bf_rne(acc[mt][nt][0] + bb);
                w.y = f2bf_rne(acc[mt][nt][1] + bb);
                w.z = f2bf_rne(acc[mt][nt][2] + bb);
                w.w = f2bf_rne(acc[mt][nt][3] + bb);
                *(ushort4*)&base[s0] = w;
            }
        }
    }
}

// ---------------------------------------------------------------------------
// Kernel 2: flash attention, FA2-style.  Block = 4 waves x 16 q-rows = 64 rows.
// grid (27, 16) x 256.  Each 64-key tile: K (4 KB) + V^T (4 KB) staged ONCE
// per block into double-buffered LDS (1 global b128 per lane per buffer);
// all 4 waves compute against it.  One barrier per tile; tile t+1 loads
// issue before compute of tile t.  Output bf16 [b][s][h][p].
// ---------------------------------------------------------------------------
__global__ __launch_bounds__(256) void attn_kernel(
    const ushort_t* __restrict__ q, const ushort_t* __restrict__ k,
    const ushort_t* __restrict__ vt, ushort_t* __restrict__ aob)
{
    const int t    = threadIdx.x;
    const int lane = t & 63;
    const int w    = t >> 6;
    const int li   = lane & 15;
    const int quad = lane >> 4;
    const int bh = blockIdx.y;
    const int b  = bh >> 3, h = bh & 7;
    const int q0 = blockIdx.x * 64 + w * 16;

    const ushort_t* __restrict__ qb = q  + (size_t)bh * SEQ * PDIM;
    const ushort_t* __restrict__ kb = k  + (size_t)bh * SEQ * PDIM;
    const ushort_t* __restrict__ vb = vt + (size_t)bh * PDIM * SEQ;

    // strides: Ks 40 ushorts (80 B, 16B-aligned rows), Vs 72 (144 B), Ps 72.
    __shared__ ushort_t Ks[2][64][40];
    __shared__ ushort_t Vs[2][32][72];
    __shared__ ushort_t Ps[4][16][72];

    const bf16x8 qfrag = *(const bf16x8*)(qb + (size_t)(q0 + li) * PDIM + quad * 8);

    // staging assignment (per lane): K row jk, 8-col chunk ck; V row pv, chunk cv
    const int jk = w * 16 + (lane >> 2), ck = (lane & 3) * 8;
    const int pv = w * 8 + (lane >> 3),  cv = (lane & 7) * 8;
    const ushort_t* kgp = kb + (size_t)jk * PDIM + ck;
    const ushort_t* vgp = vb + (size_t)pv * SEQ + cv;

    f32x4 o0 = {0.f, 0.f, 0.f, 0.f};
    f32x4 o1 = {0.f, 0.f, 0.f, 0.f};
    float m_run = -__builtin_inff(), l_run = 0.f;

    uint4 kreg = *(const uint4*)(kgp);
    uint4 vreg = *(const uint4*)(vgp);

    for (int kt = 0; kt < NKT; ++kt) {
        const int p = kt & 1;
        *(uint4*)&Ks[p][jk][ck] = kreg;
        *(uint4*)&Vs[p][pv][cv] = vreg;
        __syncthreads();
        if (kt + 1 < NKT) {
            kreg = *(const uint4*)(kgp + (size_t)(kt + 1) * 64 * PDIM);
            vreg = *(const uint4*)(vgp + (kt + 1) * 64);
        }

        // ---- S^T = K * Q^T ----
        const f32x4 zero = {0.f, 0.f, 0.f, 0.f};
        f32x4 st[4];
        #pragma unroll
        for (int jt = 0; jt < 4; ++jt) {
            const bf16x8 kf = *(const bf16x8*)&Ks[p][jt * 16 + li][quad * 8];
            st[jt] = __builtin_amdgcn_mfma_f32_16x16x32_bf16(kf, qfrag, zero, 0, 0, 0);
        }

        // ---- online softmax (per-lane stats for query col i=li) ----
        float tm = st[0][0];
        #pragma unroll
        for (int jt = 0; jt < 4; ++jt)
            #pragma unroll
            for (int r = 0; r < 4; ++r) tm = fmaxf(tm, st[jt][r]);
        tm = fmaxf(tm, __shfl_xor(tm, 16));
        tm = fmaxf(tm, __shfl_xor(tm, 32));
        const float mnew  = fmaxf(m_run, tm);
        const float negml = -(mnew * LOG2E);

        float ps = 0.f;
        #pragma unroll
        for (int jt = 0; jt < 4; ++jt) {
            const float p0 = __builtin_amdgcn_exp2f(fmaf(st[jt][0], LOG2E, negml));
            const float p1 = __builtin_amdgcn_exp2f(fmaf(st[jt][1], LOG2E, negml));
            const float p2 = __builtin_amdgcn_exp2f(fmaf(st[jt][2], LOG2E, negml));
            const float p3 = __builtin_amdgcn_exp2f(fmaf(st[jt][3], LOG2E, negml));
            ps += (p0 + p1) + (p2 + p3);
            uint2 pw;
            pw.x = __builtin_amdgcn_perm(__float_as_uint(p1) + 0x8000u,
                                         __float_as_uint(p0) + 0x8000u, 0x07060302u);
            pw.y = __builtin_amdgcn_perm(__float_as_uint(p3) + 0x8000u,
                                         __float_as_uint(p2) + 0x8000u, 0x07060302u);
            *(uint2*)&Ps[w][li][16 * jt + 4 * quad] = pw;
        }
        ps += __shfl_xor(ps, 16);
        ps += __shfl_xor(ps, 32);

        const float alpha = __builtin_amdgcn_exp2f(fmaf(m_run, LOG2E, negml));
        l_run = fmaf(l_run, alpha, ps);
        m_run = mnew;

        float af[4];
        #pragma unroll
        for (int r = 0; r < 4; ++r) af[r] = __shfl(alpha, 4 * quad + r);
        #pragma unroll
        for (int r = 0; r < 4; ++r) { o0[r] *= af[r]; o1[r] *= af[r]; }

        // ---- O += P * V  (P via LDS C->A transpose; V frags from staged LDS) ----
        const bf16x8 pa0 = *(const bf16x8*)&Ps[w][li][8 * quad];
        const bf16x8 pa1 = *(const bf16x8*)&Ps[w][li][32 + 8 * quad];
        const bf16x8 vf00 = *(const bf16x8*)&Vs[p][li][quad * 8];            // keys 0-31, p=li
        const bf16x8 vf01 = *(const bf16x8*)&Vs[p][16 + li][quad * 8];       // keys 0-31, p=16+li
        const bf16x8 vf10 = *(const bf16x8*)&Vs[p][li][32 + quad * 8];       // keys 32-63, p=li
        const bf16x8 vf11 = *(const bf16x8*)&Vs[p][16 + li][32 + quad * 8];  // keys 32-63, p=16+li
        o0 = __builtin_amdgcn_mfma_f32_16x16x32_bf16(pa0, vf00, o0, 0, 0, 0);
        o0 = __builtin_amdgcn_mfma_f32_16x16x32_bf16(pa1, vf10, o0, 0, 0, 0);
        o1 = __builtin_amdgcn_mfma_f32_16x16x32_bf16(pa0, vf01, o1, 0, 0, 0);
        o1 = __builtin_amdgcn_mfma_f32_16x16x32_bf16(pa1, vf11, o1, 0, 0, 0);
    }

    // ---- epilogue: divide by l, write bf16 [b][s][h][p] ----
    float linv[4];
    #pragma unroll
    for (int r = 0; r < 4; ++r) linv[r] = 1.0f / __shfl(l_run, 4 * quad + r);
    #pragma unroll
    for (int r = 0; r < 4; ++r) {
        const int s = q0 + 4 * quad + r;
        ushort_t* row = aob + ((size_t)(b * SEQ + s)) * EMBED + h * PDIM;
        row[li]      = f2bf_rne(o0[r] * linv[r]);
        row[16 + li] = f2bf_rne(o1[r] * linv[r]);
    }
}

// ---------------------------------------------------------------------------
// Kernel 3: output projection, bf16 MFMA, fused Wo fp32->bf16 conversion.
// grid (54, 16) x 64.  Wave tile 64(M) x 16(N), K=256.  out fp32.
// ---------------------------------------------------------------------------
__global__ __launch_bounds__(64) void out_gemm_kernel(
    const ushort_t* __restrict__ a, const float* __restrict__ Wo,
    const float* __restrict__ bo, float* __restrict__ out)
{
    const int lane = threadIdx.x, li = lane & 15, quad = lane >> 4;
    const int m0 = blockIdx.x * 64, n0 = blockIdx.y * 16;

    const ushort_t* aph = a + (size_t)(m0 + li) * EMBED + quad * 8;

    f32x4 acc[4];
    #pragma unroll
    for (int mt = 0; mt < 4; ++mt) acc[mt] = (f32x4){0.f, 0.f, 0.f, 0.f};

    #pragma unroll 2
    for (int k0 = 0; k0 < EMBED; k0 += 32) {
        bf16x8 ah[4];
        #pragma unroll
        for (int mt = 0; mt < 4; ++mt)
            ah[mt] = *(const bf16x8*)(aph + (size_t)mt * 16 * EMBED + k0);
        const float* wp = Wo + (size_t)(k0 + quad * 8) * EMBED + n0 + li;
        uint4 pb;
        uint_t* pbv = (uint_t*)&pb;
        #pragma unroll
        for (int j = 0; j < 4; ++j) {
            const uint_t u0 = __float_as_uint(wp[(size_t)(2 * j) * EMBED])     + 0x8000u;
            const uint_t u1 = __float_as_uint(wp[(size_t)(2 * j + 1) * EMBED]) + 0x8000u;
            pbv[j] = __builtin_amdgcn_perm(u1, u0, 0x07060302u);
        }
        v8cast cb; cb.u = pb;
        #pragma unroll
        for (int mt = 0; mt < 4; ++mt)
            acc[mt] = __builtin_amdgcn_mfma_f32_16x16x32_bf16(ah[mt], cb.v, acc[mt], 0, 0, 0);
    }

    const float bb = bo[n0 + li];
    #pragma unroll
    for (int mt = 0; mt < 4; ++mt)
        #pragma unroll
        for (int r = 0; r < 4; ++r) {
            const int row = m0 + mt * 16 + quad * 4 + r;
            out[(size_t)row * EMBED + n0 + li] = acc[mt][r] + bb;
        }
}

// ---------------------------------------------------------------------------
extern "C" void kernel_launch(void* const* d_in, const int* in_sizes, int n_in,
                              void* d_out, int out_size, void* d_ws, size_t ws_size,
                              hipStream_t stream)
{
    const float* x  = (const float*)d_in[0];
    const float* Wq = (const float*)d_in[1];
    const float* bq = (const float*)d_in[2];
    const float* Wk = (const float*)d_in[3];
    const float* bk = (const float*)d_in[4];
    const float* Wv = (const float*)d_in[5];
    const float* bv = (const float*)d_in[6];
    const float* Wo = (const float*)d_in[7];
    const float* bo = (const float*)d_in[8];
    float* out = (float*)d_out;

    ushort_t* ws  = (ushort_t*)d_ws;
    ushort_t* qb  = ws;                      // [b][h][s][p] bf16
    ushort_t* kb  = qb + (size_t)NE;
    ushort_t* vt  = kb + (size_t)NE;         // [b][h][p][s] bf16
    ushort_t* aob = vt + (size_t)NE;         // [b][s][h][p] bf16

    qkv_gemm_kernel<<<dim3(NTOK / 64, 8, 3), 64, 0, stream>>>(
        x, Wq, bq, Wk, bk, Wv, bv, qb, kb, vt);
    attn_kernel<<<dim3(SEQ / 64, BATCH * HEADS), 256, 0, stream>>>(qb, kb, vt, aob);
    out_gemm_kernel<<<dim3(NTOK / 64, 16), 64, 0, stream>>>(aob, Wo, bo, out);
}